// Round 4
// baseline (200.324 us; speedup 1.0000x reference)
//
#include <hip/hip_runtime.h>
#include <hip/hip_bf16.h>
#include <math.h>

// Problem constants (B=8, T=1024, C=32, F=256, D=128, K=512)
#define N_POS 8192      // B*T
#define D_DIM 128
#define K_DIM 512
#define C_DIM 32
#define F_DIM 256
#define KC    16        // k-chunks for NN
#define KPER  32        // K_DIM / KC
#define GREC_BLOCKS 256
#define GREC_COLS   8448   // 32*256 g_rec + 256 S
#define GFIN_BLOCKS 132

// ---------------------------------------------------------------- reductions
__device__ __forceinline__ float block_reduce_256(float v) {
    __shared__ float sbuf[4];
    __syncthreads();                    // protect sbuf reuse across calls
#pragma unroll
    for (int off = 32; off > 0; off >>= 1) v += __shfl_down(v, off);
    const int lane = threadIdx.x & 63;
    const int w    = threadIdx.x >> 6;
    if (lane == 0) sbuf[w] = v;
    __syncthreads();
    return (threadIdx.x == 0) ? (sbuf[0] + sbuf[1] + sbuf[2] + sbuf[3]) : 0.f;
}

// ------------------------------------- kernel 1: LDS-tiled transpose M -> MT
// grid (16 k-tiles x 4 d-tiles) = 64 blocks. Coalesced read AND write.
__global__ __launch_bounds__(256)
void transpose_m(const float* __restrict__ M, float* __restrict__ MT) {
    __shared__ float tile[32][33];
    const int k0 = (blockIdx.x & 15) * 32;
    const int d0 = (blockIdx.x >> 4) * 32;
    const int kl = threadIdx.x & 31;
    const int dl = threadIdx.x >> 5;          // 0..7
#pragma unroll
    for (int p = 0; p < 4; ++p) {
        const int d = p * 8 + dl;
        tile[d][kl] = M[(d0 + d) * K_DIM + k0 + kl];   // lanes -> k: coalesced
    }
    __syncthreads();
#pragma unroll
    for (int p = 0; p < 4; ++p) {
        const int k = p * 8 + dl;
        MT[(size_t)(k0 + k) * D_DIM + d0 + kl] = tile[kl][k];  // lanes -> d: coalesced
    }
}

// ------------------------- kernel 2: NN search, h in VGPRs, m via SMEM pipe
// grid (32 pos-blocks, KC k-chunks), 256 thr. Thread owns one (b,t); h[128]
// loaded through a VOLATILE pointer (non-rematerializable -> stays in VGPRs;
// R2's failure was the compiler sinking these loads into the k-loop, VGPR=72).
// MT rows wave-uniform -> s_load_dwordx16; VALU does only sub + add(|.|).
__global__ __launch_bounds__(256, 2)
void nn_vgpr(const float* __restrict__ H, const float* __restrict__ MT,
             float* __restrict__ pd, int* __restrict__ pi) {
    const int pos = blockIdx.x * 256 + threadIdx.x;
    const int b = pos >> 10;
    const int t = pos & 1023;
    float h[D_DIM];
    {
        const volatile float* Hb = H + (b << 17) + t;   // stride T between d
#pragma unroll
        for (int d = 0; d < D_DIM; ++d) h[d] = Hb[(size_t)(d << 10)];
    }

    const int kbase = blockIdx.y * KPER;
    float bestd = INFINITY;
    int   besti = kbase;
#pragma unroll 1
    for (int kk = 0; kk < KPER; ++kk) {
        const float* mk = MT + (size_t)(kbase + kk) * D_DIM;  // uniform -> s_load
        float a0 = 0.f, a1 = 0.f, a2 = 0.f, a3 = 0.f;
#pragma unroll
        for (int d = 0; d < D_DIM; d += 4) {
            a0 += fabsf(h[d]     - mk[d]);
            a1 += fabsf(h[d + 1] - mk[d + 1]);
            a2 += fabsf(h[d + 2] - mk[d + 2]);
            a3 += fabsf(h[d + 3] - mk[d + 3]);
        }
        const float dist = (a0 + a1) + (a2 + a3);
        if (dist < bestd) { bestd = dist; besti = kbase + kk; }  // first-min wins
    }
    pd[blockIdx.y * N_POS + pos] = bestd;
    pi[blockIdx.y * N_POS + pos] = besti;
}

// ----- kernel 3: fused tail A. Blocks 0..255: Xhat/E/loss_rec/disc-sum.
//                 Blocks 256..511: chunk-merge + memory-loss SSE.
// Both halves are block-uniform branches (no divergent __syncthreads).
__global__ __launch_bounds__(256)
void tail_a(const float* __restrict__ Hdec, const float* __restrict__ W,
            const float* __restrict__ X, const float* __restrict__ w_d,
            const float* __restrict__ H, const float* __restrict__ MT,
            const float* __restrict__ pd, const int* __restrict__ pi,
            float* __restrict__ E, float* __restrict__ accum) {
    if (blockIdx.x < 256) {
        // ---------------- xhat part ----------------
        __shared__ float Wl[C_DIM * 260];
#pragma unroll
        for (int it = 0; it < 8; ++it) {                 // stage W: 8192 floats
            const int i = it * 1024 + threadIdx.x * 4;
            const float4 v = *(const float4*)(W + i);
            *(float4*)(Wl + (i >> 8) * 260 + (i & 255)) = v;
        }
        __syncthreads();

        const int c    = threadIdx.x & 31;
        const int rg   = threadIdx.x >> 5;               // 0..7
        const int base = blockIdx.x * 32;
        const int r0 = base + rg, r1 = r0 + 8, r2 = r0 + 16, r3 = r0 + 24;

        float a0 = 0.f, a1 = 0.f, a2 = 0.f, a3 = 0.f;
#pragma unroll 4
        for (int f0 = 0; f0 < F_DIM; f0 += 4) {
            const float4 w4 = *(const float4*)(Wl + c * 260 + f0);
            const float4 h0 = *(const float4*)(Hdec + (size_t)r0 * F_DIM + f0);
            const float4 h1 = *(const float4*)(Hdec + (size_t)r1 * F_DIM + f0);
            const float4 h2 = *(const float4*)(Hdec + (size_t)r2 * F_DIM + f0);
            const float4 h3 = *(const float4*)(Hdec + (size_t)r3 * F_DIM + f0);
            a0 += h0.x * w4.x + h0.y * w4.y + h0.z * w4.z + h0.w * w4.w;
            a1 += h1.x * w4.x + h1.y * w4.y + h1.z * w4.z + h1.w * w4.w;
            a2 += h2.x * w4.x + h2.y * w4.y + h2.z * w4.z + h2.w * w4.w;
            a3 += h3.x * w4.x + h3.y * w4.y + h3.z * w4.z + h3.w * w4.w;
        }

        const float wd = w_d[c];
        float sse, dp;
        {
            const float e0 = a0 - X[(size_t)r0 * C_DIM + c];
            const float e1 = a1 - X[(size_t)r1 * C_DIM + c];
            const float e2 = a2 - X[(size_t)r2 * C_DIM + c];
            const float e3 = a3 - X[(size_t)r3 * C_DIM + c];
            E[(size_t)r0 * C_DIM + c] = e0;
            E[(size_t)r1 * C_DIM + c] = e1;
            E[(size_t)r2 * C_DIM + c] = e2;
            E[(size_t)r3 * C_DIM + c] = e3;
            sse = e0 * e0 + e1 * e1 + e2 * e2 + e3 * e3;
            dp  = (a0 + a1 + a2 + a3) * wd;
        }
        const float rA = block_reduce_256(sse);
        if (threadIdx.x == 0) atomicAdd(accum + 0, rA);
        const float rB = block_reduce_256(dp);
        if (threadIdx.x == 0) atomicAdd(accum + 1, rB);
    } else {
        // ---------------- mem-loss part ----------------
        const int local = blockIdx.x - 256;
        const int bx = local & 31;           // pos-block
        const int by = local >> 5;           // d-slice 0..7
        const int pos = bx * 256 + threadIdx.x;
        const int b = pos >> 10;
        const int t = pos & 1023;

        float bd = INFINITY;
        int   bp = 0;
#pragma unroll
        for (int p = 0; p < KC; ++p) {
            const float d = pd[p * N_POS + pos];
            if (d < bd) { bd = d; bp = p; }   // strict <: lowest chunk wins ties
        }
        const int bi = pi[bp * N_POS + pos];

        const int d0 = by * 16;
        const float* Hb = H + (b << 17) + t + (d0 << 10);
        const float* z  = MT + (size_t)bi * D_DIM + d0;
        const float4 z0 = *(const float4*)(z);
        const float4 z1 = *(const float4*)(z + 4);
        const float4 z2 = *(const float4*)(z + 8);
        const float4 z3 = *(const float4*)(z + 12);
        float s0 = 0.f, s1 = 0.f, s2 = 0.f, s3 = 0.f;
        float e;
        e = Hb[0  << 10] - z0.x; s0 += e * e;
        e = Hb[1  << 10] - z0.y; s1 += e * e;
        e = Hb[2  << 10] - z0.z; s2 += e * e;
        e = Hb[3  << 10] - z0.w; s3 += e * e;
        e = Hb[4  << 10] - z1.x; s0 += e * e;
        e = Hb[5  << 10] - z1.y; s1 += e * e;
        e = Hb[6  << 10] - z1.z; s2 += e * e;
        e = Hb[7  << 10] - z1.w; s3 += e * e;
        e = Hb[8  << 10] - z2.x; s0 += e * e;
        e = Hb[9  << 10] - z2.y; s1 += e * e;
        e = Hb[10 << 10] - z2.z; s2 += e * e;
        e = Hb[11 << 10] - z2.w; s3 += e * e;
        e = Hb[12 << 10] - z3.x; s0 += e * e;
        e = Hb[13 << 10] - z3.y; s1 += e * e;
        e = Hb[14 << 10] - z3.z; s2 += e * e;
        e = Hb[15 << 10] - z3.w; s3 += e * e;
        const float r = block_reduce_256((s0 + s1) + (s2 + s3));
        if (threadIdx.x == 0) atomicAdd(accum + 2, r);
    }
}

// --------------- kernel 4: g_rec partials (E^T Hdec) and S[f], NO atomics
__global__ __launch_bounds__(256)
void grec_s(const float* __restrict__ Hdec, const float* __restrict__ E,
            float* __restrict__ pp) {
    const int f   = threadIdx.x;
    const int bt0 = blockIdx.x * 32;
    float acc[C_DIM];
#pragma unroll
    for (int c = 0; c < C_DIM; ++c) acc[c] = 0.f;
    float sf = 0.f;
#pragma unroll 1
    for (int i = 0; i < 32; ++i) {
        const int bt = bt0 + i;
        const float hd = Hdec[(size_t)bt * F_DIM + f];   // coalesced
        sf += hd;
        const float* er = E + (size_t)bt * C_DIM;        // uniform -> s_load
#pragma unroll
        for (int c = 0; c < C_DIM; ++c) acc[c] += er[c] * hd;
    }
    float* o = pp + (size_t)blockIdx.x * GREC_COLS;
#pragma unroll
    for (int c = 0; c < C_DIM; ++c) o[c * F_DIM + f] = acc[c];
    o[8192 + f] = sf;
}

// ---- kernel 5: reduce partials -> norms, then LAST block assembles the output
// grid 132 x 256. Blocks 0..127 -> g_rec^2 (accum[3]); 128..131 -> S^2 (accum[4]).
// Last-block pattern: device-scope atomics + threadfence (G16-safe).
__global__ __launch_bounds__(256)
void grec_final(const float* __restrict__ pp, const float* __restrict__ w_d,
                float* __restrict__ accum, float* __restrict__ out) {
    const int col = blockIdx.x * 64 + (threadIdx.x & 63);
    const int pc  = threadIdx.x >> 6;                  // 0..3
    const float* base = pp + (size_t)(pc * 64) * GREC_COLS + col;
    float s = 0.f;
#pragma unroll 8
    for (int p = 0; p < 64; ++p) s += base[(size_t)p * GREC_COLS];
    __shared__ float red[4][64];
    red[pc][threadIdx.x & 63] = s;
    __syncthreads();
    if (threadIdx.x < 64) {
        const float tot = red[0][threadIdx.x] + red[1][threadIdx.x] +
                          red[2][threadIdx.x] + red[3][threadIdx.x];
        float v = tot * tot;
#pragma unroll
        for (int off = 32; off > 0; off >>= 1) v += __shfl_down(v, off);
        if (threadIdx.x == 0)
            atomicAdd(accum + ((blockIdx.x >= 128) ? 4 : 3), v);
    }

    // ---- last block to finish assembles the scalar ----
    __shared__ int is_last;
    if (threadIdx.x == 0) {
        __threadfence();
        unsigned int* cnt = (unsigned int*)(accum + 5);
        is_last = (atomicAdd(cnt, 1u) == GFIN_BLOCKS - 1);
    }
    __syncthreads();
    if (is_last) {
        float wd2 = (threadIdx.x < C_DIM) ? w_d[threadIdx.x] * w_d[threadIdx.x] : 0.f;
        if (threadIdx.x < 64) {
#pragma unroll
            for (int off = 32; off > 0; off >>= 1) wd2 += __shfl_down(wd2, off);
            if (threadIdx.x == 0) {
                __threadfence();
                const float sse_rec = atomicAdd(accum + 0, 0.f);
                const float dsum    = atomicAdd(accum + 1, 0.f);
                const float sse_mem = atomicAdd(accum + 2, 0.f);
                const float g2      = atomicAdd(accum + 3, 0.f);
                const float s2      = atomicAdd(accum + 4, 0.f);
                const float loss_rec = sse_rec / 262144.f;         // /(B*T*C)
                const float loss_d   = -dsum / 8192.f;             // -mean over B*T
                const float loss_m   = 2.f * sse_mem / 1048576.f;  // 2*SSE/(B*D*T)
                const float ngrec    = (2.f / 262144.f) * sqrtf(g2);
                const float ngd      = sqrtf(wd2 * s2) / 8192.f;
                const float lmbda    = ngrec / (ngd + 1e-6f);
                out[0] = loss_rec + loss_m + lmbda * loss_d;       // ALPHA = 1
            }
        }
    }
}

// ---------------------------------------------------------------- launcher
extern "C" void kernel_launch(void* const* d_in, const int* in_sizes, int n_in,
                              void* d_out, int out_size, void* d_ws, size_t ws_size,
                              hipStream_t stream) {
    const float* X    = (const float*)d_in[0];   // [8,1024,32]
    const float* H    = (const float*)d_in[1];   // [8,128,1024]
    const float* M    = (const float*)d_in[2];   // [128,512]
    const float* Hdec = (const float*)d_in[3];   // [8,1024,256]
    const float* W    = (const float*)d_in[4];   // [32,256]
    const float* w_d  = (const float*)d_in[5];   // [32]

    float* ws    = (float*)d_ws;
    float* MT    = ws;                      // 65536 floats
    float* E     = ws + 65536;              // 262144
    float* accum = ws + 327680;             // 16 (incl. counter at [5])
    float* pd    = ws + 327696;             // KC*8192 = 131072
    int*   pi    = (int*)(ws + 458768);     // 131072
    float* pp    = ws + 589840;             // 256*8448 = 2162688 (~10.5 MB total)

    hipMemsetAsync(accum, 0, 16 * sizeof(float), stream);

    transpose_m <<<64,             256, 0, stream>>>(M, MT);
    nn_vgpr     <<<dim3(32, KC),   256, 0, stream>>>(H, MT, pd, pi);
    tail_a      <<<512,            256, 0, stream>>>(Hdec, W, X, w_d, H, MT,
                                                     pd, pi, E, accum);
    grec_s      <<<GREC_BLOCKS,    256, 0, stream>>>(Hdec, E, pp);
    grec_final  <<<GFIN_BLOCKS,    256, 0, stream>>>(pp, w_d, accum, (float*)d_out);
}

// Round 5
// 132.946 us; speedup vs baseline: 1.5068x; 1.5068x over previous
//
#include <hip/hip_runtime.h>
#include <hip/hip_bf16.h>
#include <math.h>

// Problem constants (B=8, T=1024, C=32, F=256, D=128, K=512)
#define N_POS 8192      // B*T
#define D_DIM 128
#define K_DIM 512
#define C_DIM 32
#define F_DIM 256
#define NKT   4         // k-tiles (128 wide each)
#define GREC_COLS 8448  // 32*256 g_rec + 256 S
#define L2_BLOCKS 388   // 256 sse + 128 grec + 4 S

// ---------------------------------------------------------------- reductions
__device__ __forceinline__ float block_reduce_256(float v) {
    __shared__ float sbuf[4];
    __syncthreads();
#pragma unroll
    for (int off = 32; off > 0; off >>= 1) v += __shfl_down(v, off);
    const int lane = threadIdx.x & 63;
    const int w    = threadIdx.x >> 6;
    if (lane == 0) sbuf[w] = v;
    __syncthreads();
    return (threadIdx.x == 0) ? (sbuf[0] + sbuf[1] + sbuf[2] + sbuf[3]) : 0.f;
}

// =====================  L1: NN (blocks 0..255) + XHAT/GREC (256..511) =======
// NN: 128 pos x 128 k tile, 8x8 acc/thread, d-chunked 32-row LDS panels.
// Per d: 4 ds_read_b128 (48 LDS-cyc) vs 128 VALU (256 cyc) -> VALU-bound
// (R3's 4x4 tile was LDS-bound at 96 vs 64). Argmin uses lexicographic
// (dist, k) everywhere -> exact first-min semantics, order-independent.
// XG: xhat + E(LDS) + in-block E^T*Hdec partials; first 64 blocks also
// transpose M->MT for L2's gather.
__global__ __launch_bounds__(256)
void fused_l1(const float* __restrict__ H, const float* __restrict__ M,
              const float* __restrict__ Hdec, const float* __restrict__ W,
              const float* __restrict__ X, const float* __restrict__ w_d,
              float* __restrict__ MT, float* __restrict__ pd,
              int* __restrict__ pi, float* __restrict__ pp,
              float* __restrict__ accum) {
    __shared__ __align__(16) char smem_raw[49152];
    const int tid = threadIdx.x;

    if (blockIdx.x < 256) {
        // ------------------------------- NN tile -------------------------------
        float* hT = (float*)smem_raw;        // [32][128]
        float* mT = hT + 4096;               // [32][128]
        float* rd = mT + 4096;               // [16][128]
        int*   ri = (int*)(rd + 2048);       // [16][128]

        const int ptile = blockIdx.x >> 2;   // 64 pos-tiles
        const int ktile = blockIdx.x & 3;    // 4 k-tiles
        const int pos0  = ptile << 7;
        const int b     = pos0 >> 10;
        const int t0    = pos0 & 1023;
        const int k0    = ktile << 7;
        const float* Hb = H + (b << 17) + t0;

        const int tq = (tid & 31) << 2;      // staging col (float4)
        const int dq = tid >> 5;             // staging row 0..7
        const int p4 = (tid & 15) << 2;      // compute pos quad
        const int q4 = (tid >> 4) << 2;      // compute k quad

        float acc[8][8];
#pragma unroll
        for (int i = 0; i < 8; ++i)
#pragma unroll
            for (int j = 0; j < 8; ++j) acc[i][j] = 0.f;

        for (int ch = 0; ch < 4; ++ch) {
            const int d0 = ch << 5;
            __syncthreads();
#pragma unroll
            for (int p = 0; p < 4; ++p) {
                const int d = (p << 3) + dq;
                *(float4*)(hT + (d << 7) + tq) =
                    *(const float4*)(Hb + ((size_t)(d0 + d) << 10) + tq);
                *(float4*)(mT + (d << 7) + tq) =
                    *(const float4*)(M + (size_t)(d0 + d) * K_DIM + k0 + tq);
            }
            __syncthreads();
#pragma unroll 2
            for (int d = 0; d < 32; ++d) {
                const float4 ha = *(const float4*)(hT + (d << 7) + p4);
                const float4 hc = *(const float4*)(hT + (d << 7) + 64 + p4);
                const float4 ma = *(const float4*)(mT + (d << 7) + q4);
                const float4 mc = *(const float4*)(mT + (d << 7) + 64 + q4);
                const float hh[8] = {ha.x, ha.y, ha.z, ha.w, hc.x, hc.y, hc.z, hc.w};
                const float mm[8] = {ma.x, ma.y, ma.z, ma.w, mc.x, mc.y, mc.z, mc.w};
#pragma unroll
                for (int i = 0; i < 8; ++i)
#pragma unroll
                    for (int j = 0; j < 8; ++j)
                        acc[i][j] += fabsf(hh[i] - mm[j]);
            }
        }

        // per-thread argmin over its 8 ks (j ascending = k ascending; strict <)
#pragma unroll
        for (int i = 0; i < 8; ++i) {
            const int pl = (i < 4) ? (p4 + i) : (64 + p4 + i - 4);
            float bd = acc[i][0];
            int   bj = 0;
#pragma unroll
            for (int j = 1; j < 8; ++j)
                if (acc[i][j] < bd) { bd = acc[i][j]; bj = j; }
            const int bk = k0 + ((bj < 4) ? (q4 + bj) : (64 + q4 + bj - 4));
            rd[(tid >> 4) * 128 + pl] = bd;
            ri[(tid >> 4) * 128 + pl] = bk;
        }
        __syncthreads();

        // cross-thread merge: 16 k-groups, lexicographic (dist, k)
        if (tid < 128) {
            float bd = rd[tid];
            int   bi = ri[tid];
#pragma unroll
            for (int q = 1; q < 16; ++q) {
                const float d = rd[q * 128 + tid];
                const int   k = ri[q * 128 + tid];
                if (d < bd || (d == bd && k < bi)) { bd = d; bi = k; }
            }
            pd[ktile * N_POS + pos0 + tid] = bd;
            pi[ktile * N_POS + pos0 + tid] = bi;
        }
    } else {
        // --------------------- XHAT + E(LDS) + GREC partials -------------------
        float* Wl = (float*)smem_raw;        // [32][260]
        float* El = Wl + C_DIM * 260;        // [32][32]
        const int xb  = blockIdx.x - 256;
        const int bt0 = xb << 5;

        // first 64 xg blocks transpose one 8-d x 512-k slab of M into MT
        if (xb < 64) {
            const int d0 = xb << 1;          // 2 d-rows per block, 512 k each
            const int d  = d0 + (tid >> 7);
            const int k  = (tid & 127) << 2;
#pragma unroll
            for (int j = 0; j < 4; ++j)
                MT[(size_t)(k + j) * D_DIM + d] = M[(size_t)d * K_DIM + k + j];
        }

        // stage W into LDS (stride 260)
#pragma unroll
        for (int it = 0; it < 8; ++it) {
            const int i = it * 1024 + tid * 4;
            const float4 v = *(const float4*)(W + i);
            *(float4*)(Wl + (i >> 8) * 260 + (i & 255)) = v;
        }
        __syncthreads();

        const int c  = tid & 31;
        const int rg = tid >> 5;
        const int r0 = bt0 + rg, r1 = r0 + 8, r2 = r0 + 16, r3 = r0 + 24;

        float a0 = 0.f, a1 = 0.f, a2 = 0.f, a3 = 0.f;
#pragma unroll 4
        for (int f0 = 0; f0 < F_DIM; f0 += 4) {
            const float4 w4 = *(const float4*)(Wl + c * 260 + f0);
            const float4 h0 = *(const float4*)(Hdec + (size_t)r0 * F_DIM + f0);
            const float4 h1 = *(const float4*)(Hdec + (size_t)r1 * F_DIM + f0);
            const float4 h2 = *(const float4*)(Hdec + (size_t)r2 * F_DIM + f0);
            const float4 h3 = *(const float4*)(Hdec + (size_t)r3 * F_DIM + f0);
            a0 += h0.x * w4.x + h0.y * w4.y + h0.z * w4.z + h0.w * w4.w;
            a1 += h1.x * w4.x + h1.y * w4.y + h1.z * w4.z + h1.w * w4.w;
            a2 += h2.x * w4.x + h2.y * w4.y + h2.z * w4.z + h2.w * w4.w;
            a3 += h3.x * w4.x + h3.y * w4.y + h3.z * w4.z + h3.w * w4.w;
        }

        const float wd = w_d[c];
        const float e0 = a0 - X[(size_t)r0 * C_DIM + c];
        const float e1 = a1 - X[(size_t)r1 * C_DIM + c];
        const float e2 = a2 - X[(size_t)r2 * C_DIM + c];
        const float e3 = a3 - X[(size_t)r3 * C_DIM + c];
        El[(rg)      * 32 + c] = e0;
        El[(rg + 8)  * 32 + c] = e1;
        El[(rg + 16) * 32 + c] = e2;
        El[(rg + 24) * 32 + c] = e3;
        const float sse = e0 * e0 + e1 * e1 + e2 * e2 + e3 * e3;
        const float dp  = (a0 + a1 + a2 + a3) * wd;
        const float rA = block_reduce_256(sse);
        if (tid == 0) atomicAdd(accum + 0, rA);
        const float rB = block_reduce_256(dp);
        if (tid == 0) atomicAdd(accum + 1, rB);
        __syncthreads();   // El fully visible

        // grec: thread = f; E rows via LDS float4 broadcast
        const int f = tid;
        float gacc[C_DIM];
#pragma unroll
        for (int cc = 0; cc < C_DIM; ++cc) gacc[cc] = 0.f;
        float sf = 0.f;
#pragma unroll 1
        for (int i = 0; i < 32; ++i) {
            const float hd = Hdec[(size_t)(bt0 + i) * F_DIM + f];   // coalesced
            sf += hd;
#pragma unroll
            for (int c4 = 0; c4 < 8; ++c4) {
                const float4 e4 = *(const float4*)(El + i * 32 + c4 * 4);
                gacc[c4 * 4 + 0] += e4.x * hd;
                gacc[c4 * 4 + 1] += e4.y * hd;
                gacc[c4 * 4 + 2] += e4.z * hd;
                gacc[c4 * 4 + 3] += e4.w * hd;
            }
        }
        float* o = pp + (size_t)xb * GREC_COLS;
#pragma unroll
        for (int cc = 0; cc < C_DIM; ++cc) o[cc * F_DIM + f] = gacc[cc];
        o[8192 + f] = sf;
    }
}

// ============ L2: merge+SSE (0..255), norm reduce (256..387), assemble ======
__global__ __launch_bounds__(256)
void fused_l2(const float* __restrict__ H, const float* __restrict__ MT,
              const float* __restrict__ pd, const int* __restrict__ pi,
              const float* __restrict__ pp, const float* __restrict__ w_d,
              float* __restrict__ accum, float* __restrict__ out) {
    const int tid = threadIdx.x;
    if (blockIdx.x < 256) {
        // ---------------- chunk-merge + memory-loss SSE ----------------
        const int bx = blockIdx.x & 31;      // pos-block
        const int by = blockIdx.x >> 5;      // d-slice 0..7
        const int pos = bx * 256 + tid;
        const int b = pos >> 10;
        const int t = pos & 1023;

        float bd = INFINITY;
        int   bi = 0x7fffffff;
#pragma unroll
        for (int p = 0; p < NKT; ++p) {
            const float d = pd[p * N_POS + pos];
            const int   k = pi[p * N_POS + pos];
            if (d < bd || (d == bd && k < bi)) { bd = d; bi = k; }
        }

        const int d0 = by * 16;
        const float* Hb = H + (b << 17) + t + (d0 << 10);
        const float* z  = MT + (size_t)bi * D_DIM + d0;
        const float4 z0 = *(const float4*)(z);
        const float4 z1 = *(const float4*)(z + 4);
        const float4 z2 = *(const float4*)(z + 8);
        const float4 z3 = *(const float4*)(z + 12);
        float s0 = 0.f, s1 = 0.f, s2 = 0.f, s3 = 0.f;
        float e;
        e = Hb[0  << 10] - z0.x; s0 += e * e;
        e = Hb[1  << 10] - z0.y; s1 += e * e;
        e = Hb[2  << 10] - z0.z; s2 += e * e;
        e = Hb[3  << 10] - z0.w; s3 += e * e;
        e = Hb[4  << 10] - z1.x; s0 += e * e;
        e = Hb[5  << 10] - z1.y; s1 += e * e;
        e = Hb[6  << 10] - z1.z; s2 += e * e;
        e = Hb[7  << 10] - z1.w; s3 += e * e;
        e = Hb[8  << 10] - z2.x; s0 += e * e;
        e = Hb[9  << 10] - z2.y; s1 += e * e;
        e = Hb[10 << 10] - z2.z; s2 += e * e;
        e = Hb[11 << 10] - z2.w; s3 += e * e;
        e = Hb[12 << 10] - z3.x; s0 += e * e;
        e = Hb[13 << 10] - z3.y; s1 += e * e;
        e = Hb[14 << 10] - z3.z; s2 += e * e;
        e = Hb[15 << 10] - z3.w; s3 += e * e;
        const float r = block_reduce_256((s0 + s1) + (s2 + s3));
        if (tid == 0) atomicAdd(accum + 2, r);
    } else {
        // ---------------- norm reductions over pp ----------------
        const int g = blockIdx.x - 256;                // 0..131
        const int col = (g < 128) ? (g * 64 + (tid & 63))
                                  : (8192 + (g - 128) * 64 + (tid & 63));
        const int pc  = tid >> 6;                      // 0..3
        const float* base = pp + (size_t)(pc * 64) * GREC_COLS + col;
        float s = 0.f;
#pragma unroll 8
        for (int p = 0; p < 64; ++p) s += base[(size_t)p * GREC_COLS];
        __shared__ float red[4][64];
        red[pc][tid & 63] = s;
        __syncthreads();
        if (tid < 64) {
            const float tot = red[0][tid] + red[1][tid] +
                              red[2][tid] + red[3][tid];
            float v = tot * tot;
#pragma unroll
            for (int off = 32; off > 0; off >>= 1) v += __shfl_down(v, off);
            if (tid == 0)
                atomicAdd(accum + ((g >= 128) ? 4 : 3), v);
        }
    }

    // ---- last block to finish assembles the scalar (R4-validated) ----
    __shared__ int is_last;
    if (tid == 0) {
        __threadfence();
        unsigned int* cnt = (unsigned int*)(accum + 5);
        is_last = (atomicAdd(cnt, 1u) == L2_BLOCKS - 1);
    }
    __syncthreads();
    if (is_last && tid < 64) {
        float wd2 = (tid < C_DIM) ? w_d[tid] * w_d[tid] : 0.f;
#pragma unroll
        for (int off = 32; off > 0; off >>= 1) wd2 += __shfl_down(wd2, off);
        if (tid == 0) {
            __threadfence();
            const float sse_rec = atomicAdd(accum + 0, 0.f);
            const float dsum    = atomicAdd(accum + 1, 0.f);
            const float sse_mem = atomicAdd(accum + 2, 0.f);
            const float g2      = atomicAdd(accum + 3, 0.f);
            const float s2      = atomicAdd(accum + 4, 0.f);
            const float loss_rec = sse_rec / 262144.f;         // /(B*T*C)
            const float loss_d   = -dsum / 8192.f;             // -mean over B*T
            const float loss_m   = 2.f * sse_mem / 1048576.f;  // 2*SSE/(B*D*T)
            const float ngrec    = (2.f / 262144.f) * sqrtf(g2);
            const float ngd      = sqrtf(wd2 * s2) / 8192.f;
            const float lmbda    = ngrec / (ngd + 1e-6f);
            out[0] = loss_rec + loss_m + lmbda * loss_d;       // ALPHA = 1
        }
    }
}

// ---------------------------------------------------------------- launcher
extern "C" void kernel_launch(void* const* d_in, const int* in_sizes, int n_in,
                              void* d_out, int out_size, void* d_ws, size_t ws_size,
                              hipStream_t stream) {
    const float* X    = (const float*)d_in[0];   // [8,1024,32]
    const float* H    = (const float*)d_in[1];   // [8,128,1024]
    const float* M    = (const float*)d_in[2];   // [128,512]
    const float* Hdec = (const float*)d_in[3];   // [8,1024,256]
    const float* W    = (const float*)d_in[4];   // [32,256]
    const float* w_d  = (const float*)d_in[5];   // [32]

    float* ws    = (float*)d_ws;
    float* MT    = ws;                      // 65536 floats
    float* accum = ws + 65536;              // 16 (counter at [5])
    float* pd    = ws + 65552;              // 4*8192 = 32768
    int*   pi    = (int*)(ws + 98320);      // 32768
    float* pp    = ws + 131088;             // 256*8448 = 2162688  (~9.2 MB total)

    hipMemsetAsync(accum, 0, 16 * sizeof(float), stream);
    fused_l1<<<512,       256, 0, stream>>>(H, M, Hdec, W, X, w_d,
                                            MT, pd, pi, pp, accum);
    fused_l2<<<L2_BLOCKS, 256, 0, stream>>>(H, MT, pd, pi, pp, w_d,
                                            accum, (float*)d_out);
}